// Round 5
// baseline (179.745 us; speedup 1.0000x reference)
//
#include <hip/hip_runtime.h>
#include <hip/hip_fp16.h>

// MPM P2G, per-XCD per-tile dense lists + LDS-tiled gather (R6 design, R8 fix).
//
// node[g] = sum over particles in cells {g-1,g}^3 of trilinear w * (m, m*v)
// cell/node id: z + x*128 + y*128*128   (reference get_hash, dim==3)
//
// R2 counters: place WRITE_SIZE stuck at 62MB (= 1M records x 64B line
// write-back) -- the 4 record slots of each 64B line are written from
// DIFFERENT XCDs, whose L2s are not coherent, so lines never merge.
//   K1 place : sub-list = (xcd = blockIdx&7, tile). All writers of a 64B
//              line share one XCD's L2 -> stores merge; active write
//              region 3MB/XCD (L2-resident). NT input loads keep the
//              stream from evicting dirty lines. ~18MB write-back.
//   K2 gather: block = 8x8x8 nodes. 8 covering tiles x 8 xcd-sublists =
//              64 ragged segments; LDS offset table + binary search ->
//              grid-stride the concatenated ~1950 records (no lane idle),
//              LDS-scatter to per-cell planes, register accumulate,
//              NT coalesced store. Per-cell overflow (cnt>MAXCAP) goes
//              to an LDS node accumulator (order-independent).
//   K3 fixup : sub-list overflow (~50 particles) exact fp32 atomics.
// Fallback: counting-sort pipeline (verified), then naive scatter.
//
// R4 fix: __builtin_nontemporal_store rejects struct float4 -> store via
// ext_vector_type(4) alias (same 16B layout/alignment).

#define GRID_DIM   128
#define NUM_CELLS  (GRID_DIM * GRID_DIM * GRID_DIM)   // 2,097,152
#define INV_CELL   64.0f
#define OVF_MAX    65536
#define SCAN_BLKS  2048

#define TDIM       16           // tiles per axis (128/8)
#define NTILES     (TDIM * TDIM * TDIM)               // 4096
#define NXCD       8
#define XCAP       48           // records per (xcd,tile): mean ~32, ~3 sigma
#define MAXCAP     3            // per-cell LDS slots (P(cnt>3) ~ 0.13%)
#define NSC        729          // 9*9*9 staged cells per node tile
#define PLANE      736          // LDS word-plane stride (mult of 32)

typedef float floatx4 __attribute__((ext_vector_type(4)));

__device__ __forceinline__ int cell_id(int ix, int iy, int iz) {
    return iz + ix * GRID_DIM + iy * (GRID_DIM * GRID_DIM);
}

__device__ __forceinline__ unsigned int q16(float f) {
    int q = (int)(f * 65536.0f + 0.5f);
    return (unsigned int)min(q, 65535);
}
__device__ __forceinline__ unsigned int f2h(float f) {
    return (unsigned int)__half_as_ushort(__float2half(f));
}
__device__ __forceinline__ float h2f(unsigned int b) {
    return __half2float(__ushort_as_half((unsigned short)(b & 0xffffu)));
}

// ---- K1: per-XCD per-tile dense placement ---------------------------------
__global__ __launch_bounds__(256) void xcd_place_kernel(
    const float* __restrict__ pos, const float* __restrict__ vel,
    const float* __restrict__ mass, unsigned int* __restrict__ tile_cnt,
    uint4* __restrict__ lists, int* __restrict__ ovf_cnt,
    int* __restrict__ ovf_list, int n)
{
    int i = blockIdx.x * 256 + threadIdx.x;
    if (i >= n) return;
    int xcd = blockIdx.x & (NXCD - 1);   // round-robin wg->XCD mapping
    float px = __builtin_nontemporal_load(&pos[3 * i + 0]);
    float py = __builtin_nontemporal_load(&pos[3 * i + 1]);
    float pz = __builtin_nontemporal_load(&pos[3 * i + 2]);
    float rx = px * INV_CELL, ry = py * INV_CELL, rz = pz * INV_CELL;
    float bx = floorf(rx), by = floorf(ry), bz = floorf(rz);
    float fx = rx - bx, fy = ry - by, fz = rz - bz;   // in [0,1)
    int ix = min(max((int)bx, 0), GRID_DIM - 1);
    int iy = min(max((int)by, 0), GRID_DIM - 1);
    int iz = min(max((int)bz, 0), GRID_DIM - 1);
    int tile = (iz >> 3) | ((ix >> 3) << 4) | ((iy >> 3) << 8);
    int sub = (xcd << 12) | tile;
    unsigned int s = atomicAdd(&tile_cnt[sub], 1u);
    if (s < (unsigned int)XCAP) {
        float m  = __builtin_nontemporal_load(&mass[i]);
        float vx = __builtin_nontemporal_load(&vel[3 * i + 0]);
        float vy = __builtin_nontemporal_load(&vel[3 * i + 1]);
        float vz = __builtin_nontemporal_load(&vel[3 * i + 2]);
        unsigned int lid = (unsigned int)((iz & 7) | ((ix & 7) << 3)
                                                   | ((iy & 7) << 6));
        uint4 r;
        r.x = q16(fx) | (q16(fy) << 16);
        r.y = q16(fz) | (f2h(m) << 16);
        r.z = f2h(vx) | (f2h(vy) << 16);
        r.w = f2h(vz) | (lid << 16);
        lists[(size_t)sub * XCAP + (int)s] = r;   // regular store: L2-combine
    } else {
        int o = atomicAdd(ovf_cnt, 1);
        if (o < OVF_MAX) ovf_list[o] = i;
    }
}

// ---- K2: concatenated-segment node gather ---------------------------------
// Block = 8x8x8 node tile (512 threads). 64 sub-segments -> offset table ->
// grid-stride concatenated records, LDS scatter, register accumulate.
__global__ __launch_bounds__(512) void xcd_gather_kernel(
    const uint4* __restrict__ lists, const unsigned int* __restrict__ tile_cnt,
    float4* __restrict__ out)
{
    __shared__ unsigned int cnt_s[NSC];
    __shared__ unsigned int rec_s[4 * MAXCAP * PLANE];   // 35.3 KB
    __shared__ float nacc[4 * 512];                      // 8 KB overflow acc
    __shared__ unsigned int seg_off[65];
    __shared__ unsigned int seg_cnt[64];

    int tid = threadIdx.x;
    // XCD-chunked swizzle (4096 % 8 == 0 -> simple bijective form)
    int swz = (blockIdx.x & 7) * 512 + (blockIdx.x >> 3);
    int bz = swz & 15;
    int bx = (swz >> 4) & 15;
    int by = swz >> 8;
    int g0x = bx * 8, g0y = by * 8, g0z = bz * 8;

    for (int sc = tid; sc < NSC; sc += 512) cnt_s[sc] = 0;
    nacc[tid] = 0.0f; nacc[512 + tid] = 0.0f;
    nacc[1024 + tid] = 0.0f; nacc[1536 + tid] = 0.0f;

    // segment s = lt*8 + xcd; lt bits (lty,ltx,ltz) pick tile (b-1+lt*)
    if (tid < 64) {
        int xcd = tid & 7, lt = tid >> 3;
        int ltz = lt & 1, ltx = (lt >> 1) & 1, lty = lt >> 2;
        int tz_ = bz - 1 + ltz, tx_ = bx - 1 + ltx, ty_ = by - 1 + lty;
        unsigned int c = 0;
        if ((tz_ >= 0) & (tx_ >= 0) & (ty_ >= 0)) {
            int tile = tz_ + (tx_ << 4) + (ty_ << 8);
            c = min(tile_cnt[(xcd << 12) | tile], (unsigned int)XCAP);
        }
        seg_cnt[tid] = c;
    }
    __syncthreads();
    if (tid == 0) {
        unsigned int run = 0;
        for (int s = 0; s < 64; ++s) { seg_off[s] = run; run += seg_cnt[s]; }
        seg_off[64] = run;
    }
    __syncthreads();
    int R = (int)seg_off[64];

    // ---- stage: grid-stride the concatenated records ----------------------
    for (int r = tid; r < R; r += 512) {
        int s = 0;
        #pragma unroll
        for (int step = 32; step >= 1; step >>= 1)
            if (seg_off[s + step] <= (unsigned int)r) s += step;
        int xcd = s & 7, lt = s >> 3;
        int ltz = lt & 1, ltx = (lt >> 1) & 1, lty = lt >> 2;
        int tz_ = bz - 1 + ltz, tx_ = bx - 1 + ltx, ty_ = by - 1 + lty;
        int tile = tz_ + (tx_ << 4) + (ty_ << 8);
        int j = r - (int)seg_off[s];
        uint4 rec = lists[(size_t)((xcd << 12) | tile) * XCAP + j];
        unsigned int lid = rec.w >> 16;
        int cz = tz_ * 8 + (int)(lid & 7u);
        int cx = tx_ * 8 + (int)((lid >> 3) & 7u);
        int cy = ty_ * 8 + (int)(lid >> 6);
        int uz = cz - (g0z - 1), ux = cx - (g0x - 1), uy = cy - (g0y - 1);
        if (((unsigned)uz < 9u) & ((unsigned)ux < 9u) & ((unsigned)uy < 9u)) {
            int sc = uy * 81 + ux * 9 + uz;
            unsigned int j2 = atomicAdd(&cnt_s[sc], 1u);
            if (j2 < MAXCAP) {
                rec_s[(0 * MAXCAP + j2) * PLANE + sc] = rec.x;
                rec_s[(1 * MAXCAP + j2) * PLANE + sc] = rec.y;
                rec_s[(2 * MAXCAP + j2) * PLANE + sc] = rec.z;
                rec_s[(3 * MAXCAP + j2) * PLANE + sc] = rec.w;
            } else {
                // rare: accumulate directly into LDS node accumulators
                float fx = (float)(rec.x & 0xffffu) * (1.0f / 65536.0f);
                float fy = (float)(rec.x >> 16)     * (1.0f / 65536.0f);
                float fz = (float)(rec.y & 0xffffu) * (1.0f / 65536.0f);
                float m  = h2f(rec.y >> 16);
                float vx = h2f(rec.z), vy = h2f(rec.z >> 16), vz = h2f(rec.w);
                #pragma unroll
                for (int oy = 0; oy < 2; ++oy)
                #pragma unroll
                for (int ox = 0; ox < 2; ++ox)
                #pragma unroll
                for (int oz = 0; oz < 2; ++oz) {
                    int pz = cz + oz - g0z;
                    int px = cx + ox - g0x;
                    int py = cy + oy - g0y;
                    if (((unsigned)pz < 8u) & ((unsigned)px < 8u) &
                        ((unsigned)py < 8u)) {
                        float w = (ox ? fx : 1.0f - fx) *
                                  (oy ? fy : 1.0f - fy) *
                                  (oz ? fz : 1.0f - fz);
                        float sm = w * m;
                        int idx = py * 64 + px * 8 + pz;
                        atomicAdd(&nacc[0 * 512 + idx], sm);
                        atomicAdd(&nacc[1 * 512 + idx], sm * vx);
                        atomicAdd(&nacc[2 * 512 + idx], sm * vy);
                        atomicAdd(&nacc[3 * 512 + idx], sm * vz);
                    }
                }
            }
        }
    }
    __syncthreads();

    // ---- accumulate: thread owns node (tx,ty,tz) = tid --------------------
    int tz = tid & 7, tx = (tid >> 3) & 7, ty = tid >> 6;
    float a0 = nacc[tid], a1 = nacc[512 + tid];
    float a2 = nacc[1024 + tid], a3 = nacc[1536 + tid];

    #pragma unroll
    for (int dy = 0; dy < 2; ++dy) {
        #pragma unroll
        for (int dx = 0; dx < 2; ++dx) {
            int scb = (ty + dy) * 81 + (tx + dx) * 9 + tz;
            #pragma unroll
            for (int dz = 0; dz < 2; ++dz) {
                int sc = scb + dz;
                int cnt = min((int)cnt_s[sc], MAXCAP);
                for (int j = 0; j < cnt; ++j) {
                    unsigned r0 = rec_s[(0 * MAXCAP + j) * PLANE + sc];
                    unsigned r1 = rec_s[(1 * MAXCAP + j) * PLANE + sc];
                    unsigned r2 = rec_s[(2 * MAXCAP + j) * PLANE + sc];
                    unsigned r3 = rec_s[(3 * MAXCAP + j) * PLANE + sc];
                    float fx = (float)(r0 & 0xffffu) * (1.0f / 65536.0f);
                    float fy = (float)(r0 >> 16)     * (1.0f / 65536.0f);
                    float fz = (float)(r1 & 0xffffu) * (1.0f / 65536.0f);
                    // dx==1 -> staged cell == node's own cell -> (1-frac)
                    float wx = dx ? (1.0f - fx) : fx;
                    float wy = dy ? (1.0f - fy) : fy;
                    float wz = dz ? (1.0f - fz) : fz;
                    float sm = wx * wy * wz * h2f(r1 >> 16);
                    a0 += sm;
                    a1 += sm * h2f(r2);
                    a2 += sm * h2f(r2 >> 16);
                    a3 += sm * h2f(r3);
                }
            }
        }
    }
    int id = (g0z + tz) + (g0x + tx) * GRID_DIM
           + (g0y + ty) * (GRID_DIM * GRID_DIM);
    floatx4 v = { a0, a1, a2, a3 };
    __builtin_nontemporal_store(v, (floatx4*)&out[id]);
}

// ---- K3: sub-list overflow fixup (exact fp32, rare) -----------------------
__global__ __launch_bounds__(256) void fixup_kernel(
    const float* __restrict__ pos, const float* __restrict__ vel,
    const float* __restrict__ mass, const int* __restrict__ ovf_cnt,
    const int* __restrict__ ovf_list, float* __restrict__ out)
{
    int total = min(*ovf_cnt, OVF_MAX);
    for (int k = blockIdx.x * 256 + threadIdx.x; k < total; k += gridDim.x * 256) {
        int i = ovf_list[k];
        float px = pos[3 * i + 0] * INV_CELL;
        float py = pos[3 * i + 1] * INV_CELL;
        float pz = pos[3 * i + 2] * INV_CELL;
        float bx = floorf(px), by = floorf(py), bz = floorf(pz);
        float fx = px - bx, fy = py - by, fz = pz - bz;
        int ix = (int)bx, iy = (int)by, iz = (int)bz;
        float m = mass[i];
        float vx = vel[3 * i + 0], vy = vel[3 * i + 1], vz = vel[3 * i + 2];
        float wx[2] = { 1.0f - fx, fx }, wy[2] = { 1.0f - fy, fy }, wz[2] = { 1.0f - fz, fz };
        #pragma unroll
        for (int a = 0; a < 2; ++a)
            #pragma unroll
            for (int b = 0; b < 2; ++b)
                #pragma unroll
                for (int c = 0; c < 2; ++c) {
                    int h = cell_id(ix + a, iy + b, iz + c);
                    bool valid = (h >= 0) && (h < NUM_CELLS);
                    int hc = min(max(h, 0), NUM_CELLS - 1);
                    float s = valid ? (wx[a] * wy[b] * wz[c]) : 0.0f;
                    float sm = s * m;
                    float* cell = out + 4 * (size_t)hc;
                    atomicAdd(cell + 0, sm);
                    atomicAdd(cell + 1, sm * vx);
                    atomicAdd(cell + 2, sm * vy);
                    atomicAdd(cell + 3, sm * vz);
                }
    }
}

// ======== fallback: counting-sort pipeline (verified) ======================
__global__ __launch_bounds__(256) void s_hist_kernel(
    const float* __restrict__ pos, int* __restrict__ counts, int n)
{
    int i = blockIdx.x * 256 + threadIdx.x;
    if (i >= n) return;
    int ix = min(max((int)floorf(pos[3 * i + 0] * INV_CELL), 0), GRID_DIM - 1);
    int iy = min(max((int)floorf(pos[3 * i + 1] * INV_CELL), 0), GRID_DIM - 1);
    int iz = min(max((int)floorf(pos[3 * i + 2] * INV_CELL), 0), GRID_DIM - 1);
    atomicAdd(&counts[cell_id(ix, iy, iz)], 1);
}

__global__ __launch_bounds__(256) void s_scan_partials_kernel(
    const int* __restrict__ counts, int* __restrict__ partials)
{
    __shared__ int red[256];
    int t = threadIdx.x;
    int4 v = ((const int4*)counts)[blockIdx.x * 256 + t];
    red[t] = v.x + v.y + v.z + v.w;
    __syncthreads();
    for (int off = 128; off > 0; off >>= 1) {
        if (t < off) red[t] += red[t + off];
        __syncthreads();
    }
    if (t == 0) partials[blockIdx.x] = red[0];
}

__global__ __launch_bounds__(1024) void s_scan_tops_kernel(int* __restrict__ partials)
{
    __shared__ int s[1024];
    int t = threadIdx.x;
    int p0 = partials[2 * t], p1 = partials[2 * t + 1];
    int sum = p0 + p1;
    s[t] = sum;
    __syncthreads();
    for (int off = 1; off < 1024; off <<= 1) {
        int x = (t >= off) ? s[t - off] : 0;
        __syncthreads();
        s[t] += x;
        __syncthreads();
    }
    int excl = s[t] - sum;
    partials[2 * t] = excl;
    partials[2 * t + 1] = excl + p0;
}

__global__ __launch_bounds__(256) void s_scan_final_kernel(
    const int* __restrict__ counts, const int* __restrict__ partials,
    int* __restrict__ offsets, int* __restrict__ cursors)
{
    __shared__ int s[256];
    int t = threadIdx.x;
    int g = blockIdx.x * 256 + t;
    int4 v = ((const int4*)counts)[g];
    int sum = v.x + v.y + v.z + v.w;
    s[t] = sum;
    __syncthreads();
    for (int off = 1; off < 256; off <<= 1) {
        int x = (t >= off) ? s[t - off] : 0;
        __syncthreads();
        s[t] += x;
        __syncthreads();
    }
    int run = partials[blockIdx.x] + s[t] - sum;
    int4 o = make_int4(run, run + v.x, run + v.x + v.y, run + v.x + v.y + v.z);
    ((int4*)offsets)[g] = o;
    ((int4*)cursors)[g] = o;
}

__global__ __launch_bounds__(256) void s_binplace_kernel(
    const float* __restrict__ pos, const float* __restrict__ vel,
    const float* __restrict__ mass, int* __restrict__ cursors,
    float4* __restrict__ records, int n)
{
    int i = blockIdx.x * 256 + threadIdx.x;
    if (i >= n) return;
    float rx = pos[3 * i + 0] * INV_CELL;
    float ry = pos[3 * i + 1] * INV_CELL;
    float rz = pos[3 * i + 2] * INV_CELL;
    int ix = min(max((int)floorf(rx), 0), GRID_DIM - 1);
    int iy = min(max((int)floorf(ry), 0), GRID_DIM - 1);
    int iz = min(max((int)floorf(rz), 0), GRID_DIM - 1);
    int slot = atomicAdd(&cursors[cell_id(ix, iy, iz)], 1);
    records[2 * slot + 0] = make_float4(rx, ry, rz, mass[i]);
    records[2 * slot + 1] = make_float4(vel[3 * i + 0], vel[3 * i + 1],
                                        vel[3 * i + 2], 0.0f);
}

__global__ __launch_bounds__(256) void s_node_gather_kernel(
    const float4* __restrict__ records, const int* __restrict__ offsets,
    const int* __restrict__ cursors, float4* __restrict__ out)
{
    int id = blockIdx.x * 256 + threadIdx.x;
    int gz = id & (GRID_DIM - 1);
    int gx = (id >> 7) & (GRID_DIM - 1);
    int gy = id >> 14;
    float fgx = (float)gx, fgy = (float)gy, fgz = (float)gz;
    float a0 = 0.0f, a1 = 0.0f, a2 = 0.0f, a3 = 0.0f;
    int z0 = max(gz - 1, 0), y0 = max(gy - 1, 0), x0 = max(gx - 1, 0);
    for (int cy = y0; cy <= gy; ++cy) {
        for (int cx = x0; cx <= gx; ++cx) {
            int cb = cx * GRID_DIM + cy * (GRID_DIM * GRID_DIM);
            int beg = offsets[cb + z0];
            int end = cursors[cb + gz];
            for (int p = beg; p < end; ++p) {
                float4 r0 = records[2 * p + 0];
                float4 r1 = records[2 * p + 1];
                float w = (1.0f - fabsf(r0.x - fgx)) *
                          (1.0f - fabsf(r0.y - fgy)) *
                          (1.0f - fabsf(r0.z - fgz));
                float sm = w * r0.w;
                a0 += sm; a1 += sm * r1.x; a2 += sm * r1.y; a3 += sm * r1.z;
            }
        }
    }
    out[id] = make_float4(a0, a1, a2, a3);
}

// ---- last-resort naive scatter --------------------------------------------
__global__ __launch_bounds__(256) void p2g_scatter_kernel(
    const float* __restrict__ pos, const float* __restrict__ vel,
    const float* __restrict__ mass, float* __restrict__ out, int n)
{
    int i = blockIdx.x * blockDim.x + threadIdx.x;
    if (i >= n) return;
    float px = pos[3 * i + 0] * INV_CELL;
    float py = pos[3 * i + 1] * INV_CELL;
    float pz = pos[3 * i + 2] * INV_CELL;
    float bx = floorf(px), by = floorf(py), bz = floorf(pz);
    float fx = px - bx, fy = py - by, fz = pz - bz;
    int ix = (int)bx, iy = (int)by, iz = (int)bz;
    float m = mass[i];
    float vx = vel[3 * i + 0], vy = vel[3 * i + 1], vz = vel[3 * i + 2];
    float wx[2] = { 1.0f - fx, fx }, wy[2] = { 1.0f - fy, fy }, wz[2] = { 1.0f - fz, fz };
    #pragma unroll
    for (int a = 0; a < 2; ++a)
        #pragma unroll
        for (int b = 0; b < 2; ++b)
            #pragma unroll
            for (int c = 0; c < 2; ++c) {
                int h = cell_id(ix + a, iy + b, iz + c);
                bool valid = (h >= 0) && (h < NUM_CELLS);
                int hc = min(max(h, 0), NUM_CELLS - 1);
                float s = valid ? (wx[a] * wy[b] * wz[c]) : 0.0f;
                float sm = s * m;
                float* cell = out + 4 * (size_t)hc;
                atomicAdd(cell + 0, sm);
                atomicAdd(cell + 1, sm * vx);
                atomicAdd(cell + 2, sm * vy);
                atomicAdd(cell + 3, sm * vz);
            }
}

extern "C" void kernel_launch(void* const* d_in, const int* in_sizes, int n_in,
                              void* d_out, int out_size, void* d_ws, size_t ws_size,
                              hipStream_t stream) {
    const float* pos  = (const float*)d_in[0];
    const float* vel  = (const float*)d_in[1];
    const float* mass = (const float*)d_in[2];
    float* out = (float*)d_out;
    int n = in_sizes[2];
    int blocks = (n + 255) / 256;

    // XCD-path ws: [tile_cnt 128KB][lists 24MB][ovf_cnt 256B][ovf_list 256KB]
    size_t x_off_lists = (size_t)NXCD * NTILES * 4;                       // 128 KB
    size_t x_off_ovf   = x_off_lists + (size_t)NXCD * NTILES * XCAP * 16; // +24 MB
    size_t need_xcd    = x_off_ovf + 256 + (size_t)OVF_MAX * 4;

    // Sorted-path ws: [counts/cursors 8MB][offsets 8MB][records n*32][partials]
    size_t s_off_offsets  = (size_t)NUM_CELLS * 4;
    size_t s_off_records  = s_off_offsets + (size_t)NUM_CELLS * 4;
    size_t s_off_partials = s_off_records + (size_t)n * 32;
    size_t need_sorted    = s_off_partials + (size_t)SCAN_BLKS * 4;

    if (ws_size >= need_xcd) {
        char* ws = (char*)d_ws;
        unsigned int* tile_cnt = (unsigned int*)ws;
        uint4* lists  = (uint4*)(ws + x_off_lists);
        int* ovf_cnt  = (int*)(ws + x_off_ovf);
        int* ovf_list = ovf_cnt + 64;

        (void)hipMemsetAsync(tile_cnt, 0, x_off_lists, stream);
        (void)hipMemsetAsync(ovf_cnt, 0, 4, stream);
        xcd_place_kernel<<<blocks, 256, 0, stream>>>(
            pos, vel, mass, tile_cnt, lists, ovf_cnt, ovf_list, n);
        xcd_gather_kernel<<<NTILES, 512, 0, stream>>>(
            lists, tile_cnt, (float4*)out);
        fixup_kernel<<<32, 256, 0, stream>>>(pos, vel, mass, ovf_cnt,
                                             ovf_list, out);
    } else if (ws_size >= need_sorted) {
        char* ws = (char*)d_ws;
        int* counts   = (int*)ws;                    // reused as cursors
        int* offsets  = (int*)(ws + s_off_offsets);
        float4* records = (float4*)(ws + s_off_records);
        int* partials = (int*)(ws + s_off_partials);

        (void)hipMemsetAsync(counts, 0, (size_t)NUM_CELLS * 4, stream);
        s_hist_kernel<<<blocks, 256, 0, stream>>>(pos, counts, n);
        s_scan_partials_kernel<<<SCAN_BLKS, 256, 0, stream>>>(counts, partials);
        s_scan_tops_kernel<<<1, 1024, 0, stream>>>(partials);
        s_scan_final_kernel<<<SCAN_BLKS, 256, 0, stream>>>(counts, partials,
                                                           offsets, counts);
        s_binplace_kernel<<<blocks, 256, 0, stream>>>(pos, vel, mass, counts,
                                                      records, n);
        s_node_gather_kernel<<<NUM_CELLS / 256, 256, 0, stream>>>(
            records, offsets, counts, (float4*)out);
    } else {
        (void)hipMemsetAsync(out, 0, (size_t)out_size * sizeof(float), stream);
        p2g_scatter_kernel<<<blocks, 256, 0, stream>>>(pos, vel, mass, out, n);
    }
}

// Round 6
// 175.736 us; speedup vs baseline: 1.0228x; 1.0228x over previous
//
#include <hip/hip_runtime.h>
#include <hip/hip_fp16.h>

// MPM P2G, per-XCD per-4^3-tile dense lists + decode-once LDS gather (R9).
//
// node[g] = sum over particles in cells {g-1,g}^3 of trilinear w * (m, m*v)
// cell/node id: z + x*128 + y*128*128   (reference get_hash, dim==3)
//
// R5 counters: gather VALU-bound (VALUBusy 70%, HBM 12%, FETCH 12.7MB).
// 82% of stage loads were out-of-halo (8^3 tiles), and records were
// re-decoded ~5.6x in accumulate. R9:
//   K1 place : 4^3 tiles (32768), sub-list = (xcd=blockIdx&7, tile),
//              XCAP=16. 2 particles/thread. Same L2 write-combining
//              (active dirty ~2.7MB/XCD < 4MB L2).
//   K2 gather: block = 8x8x8 nodes. 27 tiles x 8 xcd = 216 segments,
//              R ~824 (halo efficiency 42%). Wave-parallel seg scan.
//              Stage decodes ONCE -> LDS float4{fx,fy,fz,vx|vy} (b128)
//              + word{m|vz}; padded index e=3sc+(sc>>2) for banks.
//              Cell-overflow (cnt>3) -> small LDS list consumed by all
//              threads (order-independent). 50.7KB LDS -> 3 blocks/CU.
//   K3 fixup : sub-list overflow (~0-50 particles) exact fp32 atomics.
// Fallback: counting-sort pipeline (verified), then naive scatter.

#define GRID_DIM   128
#define NUM_CELLS  (GRID_DIM * GRID_DIM * GRID_DIM)   // 2,097,152
#define INV_CELL   64.0f
#define OVF_MAX    65536
#define SCAN_BLKS  2048

#define TDIM4      32           // 4-cell tiles per axis
#define NTILES4    (TDIM4 * TDIM4 * TDIM4)            // 32768
#define NXCD       8
#define XCAP       16           // records per (xcd,tile): mean 3.8
#define MAXCAP     3            // per-cell LDS slots (P(cnt>3) ~ 0.13%)
#define NSEG       216          // 27 tiles x 8 xcd segments
#define NREC       2369         // EPAD(728)+2 + 1
#define EPAD(sc)   ((sc) * 3 + ((sc) >> 2))

typedef float floatx4 __attribute__((ext_vector_type(4)));

__device__ __forceinline__ int cell_id(int ix, int iy, int iz) {
    return iz + ix * GRID_DIM + iy * (GRID_DIM * GRID_DIM);
}

__device__ __forceinline__ unsigned int q16(float f) {
    int q = (int)(f * 65536.0f + 0.5f);
    return (unsigned int)min(q, 65535);
}
__device__ __forceinline__ unsigned int f2h(float f) {
    return (unsigned int)__half_as_ushort(__float2half(f));
}
__device__ __forceinline__ float h2f(unsigned int b) {
    return __half2float(__ushort_as_half((unsigned short)(b & 0xffffu)));
}

// ---- K1: per-XCD per-tile dense placement (2 particles/thread) ------------
__global__ __launch_bounds__(256) void xcd_place_kernel(
    const float* __restrict__ pos, const float* __restrict__ vel,
    const float* __restrict__ mass, unsigned int* __restrict__ tile_cnt,
    uint4* __restrict__ lists, int* __restrict__ ovf_cnt,
    int* __restrict__ ovf_list, int n)
{
    int xcd = blockIdx.x & (NXCD - 1);   // round-robin wg->XCD mapping
    int i0 = blockIdx.x * 512 + threadIdx.x;
    #pragma unroll
    for (int k = 0; k < 2; ++k) {
        int i = i0 + k * 256;
        if (i < n) {
            float px = __builtin_nontemporal_load(&pos[3 * i + 0]);
            float py = __builtin_nontemporal_load(&pos[3 * i + 1]);
            float pz = __builtin_nontemporal_load(&pos[3 * i + 2]);
            float rx = px * INV_CELL, ry = py * INV_CELL, rz = pz * INV_CELL;
            float bx = floorf(rx), by = floorf(ry), bz = floorf(rz);
            float fx = rx - bx, fy = ry - by, fz = rz - bz;   // in [0,1)
            int ix = min(max((int)bx, 0), GRID_DIM - 1);
            int iy = min(max((int)by, 0), GRID_DIM - 1);
            int iz = min(max((int)bz, 0), GRID_DIM - 1);
            int tile = (iz >> 2) | ((ix >> 2) << 5) | ((iy >> 2) << 10);
            int sub = (xcd << 15) | tile;
            unsigned int s = atomicAdd(&tile_cnt[sub], 1u);
            if (s < (unsigned int)XCAP) {
                float m  = __builtin_nontemporal_load(&mass[i]);
                float vx = __builtin_nontemporal_load(&vel[3 * i + 0]);
                float vy = __builtin_nontemporal_load(&vel[3 * i + 1]);
                float vz = __builtin_nontemporal_load(&vel[3 * i + 2]);
                unsigned int lid = (unsigned int)((iz & 3) | ((ix & 3) << 2)
                                                           | ((iy & 3) << 4));
                uint4 r;
                r.x = q16(fx) | (q16(fy) << 16);
                r.y = q16(fz) | (f2h(m) << 16);
                r.z = f2h(vx) | (f2h(vy) << 16);
                r.w = f2h(vz) | (lid << 16);
                lists[(size_t)sub * XCAP + (int)s] = r;
            } else {
                int o = atomicAdd(ovf_cnt, 1);
                if (o < OVF_MAX) ovf_list[o] = i;
            }
        }
    }
}

// ---- K2: segment-streamed node gather, decode-once LDS --------------------
__global__ __launch_bounds__(512) void xcd_gather_kernel(
    const uint4* __restrict__ lists, const unsigned int* __restrict__ tile_cnt,
    float4* __restrict__ out)
{
    __shared__ float4 recA[NREC];             // {fx,fy,fz, vx|vy bits}
    __shared__ unsigned int recB[NREC];       // m | vz<<16
    __shared__ unsigned int cnt_s[729];
    __shared__ unsigned short seg_off[218];
    __shared__ int wtot[8];
    __shared__ int ovf_n;
    __shared__ short ovf_sc[64];
    __shared__ uint4 ovf_rec[64];

    int tid = threadIdx.x;
    // XCD-chunked swizzle (4096 % 8 == 0 -> simple bijective form)
    int swz = (blockIdx.x & 7) * 512 + (blockIdx.x >> 3);
    int bz = swz & 15;
    int bx = (swz >> 4) & 15;
    int by = swz >> 8;
    int g0x = bx * 8, g0y = by * 8, g0z = bz * 8;
    int Tz0 = bz * 2 - 1, Tx0 = bx * 2 - 1, Ty0 = by * 2 - 1;

    for (int s2 = tid; s2 < 729; s2 += 512) cnt_s[s2] = 0;
    if (tid == 0) ovf_n = 0;

    // ---- segment counts + wave-parallel exclusive scan --------------------
    unsigned int c = 0;
    if (tid < NSEG) {
        int xcd = tid & 7, q = tid >> 3;
        int ltz = q % 3, q2 = q / 3, ltx = q2 % 3, lty = q2 / 3;
        int tz_ = Tz0 + ltz, tx_ = Tx0 + ltx, ty_ = Ty0 + lty;
        if ((tz_ >= 0) & (tx_ >= 0) & (ty_ >= 0)) {
            int tile = tz_ | (tx_ << 5) | (ty_ << 10);
            c = min(tile_cnt[(xcd << 15) | tile], (unsigned int)XCAP);
        }
    }
    unsigned int v = c;
    #pragma unroll
    for (int d = 1; d < 64; d <<= 1) {
        unsigned int t = __shfl_up(v, d, 64);
        if ((tid & 63) >= d) v += t;
    }
    if ((tid & 63) == 63) wtot[tid >> 6] = (int)v;
    __syncthreads();
    if (tid == 0) {
        int run = 0;
        #pragma unroll
        for (int w2 = 0; w2 < 8; ++w2) { int t = wtot[w2]; wtot[w2] = run; run += t; }
    }
    __syncthreads();
    if (tid <= NSEG)
        seg_off[tid] = (unsigned short)((unsigned int)wtot[tid >> 6] + v - c);
    __syncthreads();
    int R = (int)seg_off[NSEG];

    // ---- stage: grid-stride concatenated records, decode once -------------
    for (int r = tid; r < R; r += 512) {
        int s = 0;
        #pragma unroll
        for (int step = 128; step >= 1; step >>= 1)
            if (s + step <= NSEG && (int)seg_off[s + step] <= r) s += step;
        int xcd = s & 7, q = s >> 3;
        int ltz = q % 3, q2 = q / 3, ltx = q2 % 3, lty = q2 / 3;
        int tz_ = Tz0 + ltz, tx_ = Tx0 + ltx, ty_ = Ty0 + lty;
        int tile = tz_ | (tx_ << 5) | (ty_ << 10);
        int j = r - (int)seg_off[s];
        uint4 rec = lists[(size_t)((xcd << 15) | tile) * XCAP + j];
        unsigned int lid = rec.w >> 16;
        int cz = tz_ * 4 + (int)(lid & 3u);
        int cx = tx_ * 4 + (int)((lid >> 2) & 3u);
        int cy = ty_ * 4 + (int)(lid >> 4);
        int uz = cz - (g0z - 1), ux = cx - (g0x - 1), uy = cy - (g0y - 1);
        if (((unsigned)uz < 9u) & ((unsigned)ux < 9u) & ((unsigned)uy < 9u)) {
            int sc = uy * 81 + ux * 9 + uz;
            unsigned int j2 = atomicAdd(&cnt_s[sc], 1u);
            if (j2 < MAXCAP) {
                int e = EPAD(sc) + (int)j2;
                float fx = (float)(rec.x & 0xffffu) * (1.0f / 65536.0f);
                float fy = (float)(rec.x >> 16)     * (1.0f / 65536.0f);
                float fz = (float)(rec.y & 0xffffu) * (1.0f / 65536.0f);
                recA[e] = make_float4(fx, fy, fz, __uint_as_float(rec.z));
                recB[e] = (rec.y >> 16) | (rec.w << 16);
            } else {
                int o = atomicAdd(&ovf_n, 1);
                if (o < 64) { ovf_sc[o] = (short)sc; ovf_rec[o] = rec; }
                // o>=64 needs ~64 cells in one block at cnt>3: P < 1e-80.
            }
        }
    }
    __syncthreads();

    // ---- accumulate: thread owns node (tx,ty,tz) = tid --------------------
    int tz = tid & 7, tx = (tid >> 3) & 7, ty = tid >> 6;
    float a0 = 0.0f, a1 = 0.0f, a2 = 0.0f, a3 = 0.0f;

    #pragma unroll
    for (int dy = 0; dy < 2; ++dy) {
        #pragma unroll
        for (int dx = 0; dx < 2; ++dx) {
            int scb = (ty + dy) * 81 + (tx + dx) * 9 + tz;
            #pragma unroll
            for (int dz = 0; dz < 2; ++dz) {
                int sc = scb + dz;
                int cnt = min((int)cnt_s[sc], MAXCAP);
                int eb = EPAD(sc);
                for (int j = 0; j < cnt; ++j) {
                    float4 A = recA[eb + j];
                    unsigned int B = recB[eb + j];
                    unsigned int w3 = __float_as_uint(A.w);
                    // dx==1 -> staged cell == node's own cell -> (1-frac)
                    float wx = dx ? (1.0f - A.x) : A.x;
                    float wy = dy ? (1.0f - A.y) : A.y;
                    float wz = dz ? (1.0f - A.z) : A.z;
                    float sm = wx * wy * wz * h2f(B);
                    a0 += sm;
                    a1 += sm * h2f(w3);
                    a2 += sm * h2f(w3 >> 16);
                    a3 += sm * h2f(B >> 16);
                }
            }
        }
    }

    // ---- rare per-cell overflow: every thread scans the tiny list ---------
    int no = min(ovf_n, 64);
    for (int e2 = 0; e2 < no; ++e2) {
        int sc = (int)ovf_sc[e2];
        int uzv = sc % 9, t2 = sc / 9, uxv = t2 % 9, uyv = t2 / 9;
        int ddz = uzv - tz, ddx = uxv - tx, ddy = uyv - ty;
        if (((unsigned)ddz < 2u) & ((unsigned)ddx < 2u) & ((unsigned)ddy < 2u)) {
            uint4 rec = ovf_rec[e2];
            float fx = (float)(rec.x & 0xffffu) * (1.0f / 65536.0f);
            float fy = (float)(rec.x >> 16)     * (1.0f / 65536.0f);
            float fz = (float)(rec.y & 0xffffu) * (1.0f / 65536.0f);
            float wx = ddx ? (1.0f - fx) : fx;
            float wy = ddy ? (1.0f - fy) : fy;
            float wz = ddz ? (1.0f - fz) : fz;
            float sm = wx * wy * wz * h2f(rec.y >> 16);
            a0 += sm;
            a1 += sm * h2f(rec.z);
            a2 += sm * h2f(rec.z >> 16);
            a3 += sm * h2f(rec.w);
        }
    }

    int id = (g0z + tz) + (g0x + tx) * GRID_DIM
           + (g0y + ty) * (GRID_DIM * GRID_DIM);
    floatx4 vv = { a0, a1, a2, a3 };
    __builtin_nontemporal_store(vv, (floatx4*)&out[id]);
}

// ---- K3: sub-list overflow fixup (exact fp32, rare) -----------------------
__global__ __launch_bounds__(256) void fixup_kernel(
    const float* __restrict__ pos, const float* __restrict__ vel,
    const float* __restrict__ mass, const int* __restrict__ ovf_cnt,
    const int* __restrict__ ovf_list, float* __restrict__ out)
{
    int total = min(*ovf_cnt, OVF_MAX);
    for (int k = blockIdx.x * 256 + threadIdx.x; k < total; k += gridDim.x * 256) {
        int i = ovf_list[k];
        float px = pos[3 * i + 0] * INV_CELL;
        float py = pos[3 * i + 1] * INV_CELL;
        float pz = pos[3 * i + 2] * INV_CELL;
        float bx = floorf(px), by = floorf(py), bz = floorf(pz);
        float fx = px - bx, fy = py - by, fz = pz - bz;
        int ix = (int)bx, iy = (int)by, iz = (int)bz;
        float m = mass[i];
        float vx = vel[3 * i + 0], vy = vel[3 * i + 1], vz = vel[3 * i + 2];
        float wx[2] = { 1.0f - fx, fx }, wy[2] = { 1.0f - fy, fy }, wz[2] = { 1.0f - fz, fz };
        #pragma unroll
        for (int a = 0; a < 2; ++a)
            #pragma unroll
            for (int b = 0; b < 2; ++b)
                #pragma unroll
                for (int c = 0; c < 2; ++c) {
                    int h = cell_id(ix + a, iy + b, iz + c);
                    bool valid = (h >= 0) && (h < NUM_CELLS);
                    int hc = min(max(h, 0), NUM_CELLS - 1);
                    float s = valid ? (wx[a] * wy[b] * wz[c]) : 0.0f;
                    float sm = s * m;
                    float* cell = out + 4 * (size_t)hc;
                    atomicAdd(cell + 0, sm);
                    atomicAdd(cell + 1, sm * vx);
                    atomicAdd(cell + 2, sm * vy);
                    atomicAdd(cell + 3, sm * vz);
                }
    }
}

// ======== fallback: counting-sort pipeline (verified) ======================
__global__ __launch_bounds__(256) void s_hist_kernel(
    const float* __restrict__ pos, int* __restrict__ counts, int n)
{
    int i = blockIdx.x * 256 + threadIdx.x;
    if (i >= n) return;
    int ix = min(max((int)floorf(pos[3 * i + 0] * INV_CELL), 0), GRID_DIM - 1);
    int iy = min(max((int)floorf(pos[3 * i + 1] * INV_CELL), 0), GRID_DIM - 1);
    int iz = min(max((int)floorf(pos[3 * i + 2] * INV_CELL), 0), GRID_DIM - 1);
    atomicAdd(&counts[cell_id(ix, iy, iz)], 1);
}

__global__ __launch_bounds__(256) void s_scan_partials_kernel(
    const int* __restrict__ counts, int* __restrict__ partials)
{
    __shared__ int red[256];
    int t = threadIdx.x;
    int4 v = ((const int4*)counts)[blockIdx.x * 256 + t];
    red[t] = v.x + v.y + v.z + v.w;
    __syncthreads();
    for (int off = 128; off > 0; off >>= 1) {
        if (t < off) red[t] += red[t + off];
        __syncthreads();
    }
    if (t == 0) partials[blockIdx.x] = red[0];
}

__global__ __launch_bounds__(1024) void s_scan_tops_kernel(int* __restrict__ partials)
{
    __shared__ int s[1024];
    int t = threadIdx.x;
    int p0 = partials[2 * t], p1 = partials[2 * t + 1];
    int sum = p0 + p1;
    s[t] = sum;
    __syncthreads();
    for (int off = 1; off < 1024; off <<= 1) {
        int x = (t >= off) ? s[t - off] : 0;
        __syncthreads();
        s[t] += x;
        __syncthreads();
    }
    int excl = s[t] - sum;
    partials[2 * t] = excl;
    partials[2 * t + 1] = excl + p0;
}

__global__ __launch_bounds__(256) void s_scan_final_kernel(
    const int* __restrict__ counts, const int* __restrict__ partials,
    int* __restrict__ offsets, int* __restrict__ cursors)
{
    __shared__ int s[256];
    int t = threadIdx.x;
    int g = blockIdx.x * 256 + t;
    int4 v = ((const int4*)counts)[g];
    int sum = v.x + v.y + v.z + v.w;
    s[t] = sum;
    __syncthreads();
    for (int off = 1; off < 256; off <<= 1) {
        int x = (t >= off) ? s[t - off] : 0;
        __syncthreads();
        s[t] += x;
        __syncthreads();
    }
    int run = partials[blockIdx.x] + s[t] - sum;
    int4 o = make_int4(run, run + v.x, run + v.x + v.y, run + v.x + v.y + v.z);
    ((int4*)offsets)[g] = o;
    ((int4*)cursors)[g] = o;
}

__global__ __launch_bounds__(256) void s_binplace_kernel(
    const float* __restrict__ pos, const float* __restrict__ vel,
    const float* __restrict__ mass, int* __restrict__ cursors,
    float4* __restrict__ records, int n)
{
    int i = blockIdx.x * 256 + threadIdx.x;
    if (i >= n) return;
    float rx = pos[3 * i + 0] * INV_CELL;
    float ry = pos[3 * i + 1] * INV_CELL;
    float rz = pos[3 * i + 2] * INV_CELL;
    int ix = min(max((int)floorf(rx), 0), GRID_DIM - 1);
    int iy = min(max((int)floorf(ry), 0), GRID_DIM - 1);
    int iz = min(max((int)floorf(rz), 0), GRID_DIM - 1);
    int slot = atomicAdd(&cursors[cell_id(ix, iy, iz)], 1);
    records[2 * slot + 0] = make_float4(rx, ry, rz, mass[i]);
    records[2 * slot + 1] = make_float4(vel[3 * i + 0], vel[3 * i + 1],
                                        vel[3 * i + 2], 0.0f);
}

__global__ __launch_bounds__(256) void s_node_gather_kernel(
    const float4* __restrict__ records, const int* __restrict__ offsets,
    const int* __restrict__ cursors, float4* __restrict__ out)
{
    int id = blockIdx.x * 256 + threadIdx.x;
    int gz = id & (GRID_DIM - 1);
    int gx = (id >> 7) & (GRID_DIM - 1);
    int gy = id >> 14;
    float fgx = (float)gx, fgy = (float)gy, fgz = (float)gz;
    float a0 = 0.0f, a1 = 0.0f, a2 = 0.0f, a3 = 0.0f;
    int z0 = max(gz - 1, 0), y0 = max(gy - 1, 0), x0 = max(gx - 1, 0);
    for (int cy = y0; cy <= gy; ++cy) {
        for (int cx = x0; cx <= gx; ++cx) {
            int cb = cx * GRID_DIM + cy * (GRID_DIM * GRID_DIM);
            int beg = offsets[cb + z0];
            int end = cursors[cb + gz];
            for (int p = beg; p < end; ++p) {
                float4 r0 = records[2 * p + 0];
                float4 r1 = records[2 * p + 1];
                float w = (1.0f - fabsf(r0.x - fgx)) *
                          (1.0f - fabsf(r0.y - fgy)) *
                          (1.0f - fabsf(r0.z - fgz));
                float sm = w * r0.w;
                a0 += sm; a1 += sm * r1.x; a2 += sm * r1.y; a3 += sm * r1.z;
            }
        }
    }
    out[id] = make_float4(a0, a1, a2, a3);
}

// ---- last-resort naive scatter --------------------------------------------
__global__ __launch_bounds__(256) void p2g_scatter_kernel(
    const float* __restrict__ pos, const float* __restrict__ vel,
    const float* __restrict__ mass, float* __restrict__ out, int n)
{
    int i = blockIdx.x * blockDim.x + threadIdx.x;
    if (i >= n) return;
    float px = pos[3 * i + 0] * INV_CELL;
    float py = pos[3 * i + 1] * INV_CELL;
    float pz = pos[3 * i + 2] * INV_CELL;
    float bx = floorf(px), by = floorf(py), bz = floorf(pz);
    float fx = px - bx, fy = py - by, fz = pz - bz;
    int ix = (int)bx, iy = (int)by, iz = (int)bz;
    float m = mass[i];
    float vx = vel[3 * i + 0], vy = vel[3 * i + 1], vz = vel[3 * i + 2];
    float wx[2] = { 1.0f - fx, fx }, wy[2] = { 1.0f - fy, fy }, wz[2] = { 1.0f - fz, fz };
    #pragma unroll
    for (int a = 0; a < 2; ++a)
        #pragma unroll
        for (int b = 0; b < 2; ++b)
            #pragma unroll
            for (int c = 0; c < 2; ++c) {
                int h = cell_id(ix + a, iy + b, iz + c);
                bool valid = (h >= 0) && (h < NUM_CELLS);
                int hc = min(max(h, 0), NUM_CELLS - 1);
                float s = valid ? (wx[a] * wy[b] * wz[c]) : 0.0f;
                float sm = s * m;
                float* cell = out + 4 * (size_t)hc;
                atomicAdd(cell + 0, sm);
                atomicAdd(cell + 1, sm * vx);
                atomicAdd(cell + 2, sm * vy);
                atomicAdd(cell + 3, sm * vz);
            }
}

extern "C" void kernel_launch(void* const* d_in, const int* in_sizes, int n_in,
                              void* d_out, int out_size, void* d_ws, size_t ws_size,
                              hipStream_t stream) {
    const float* pos  = (const float*)d_in[0];
    const float* vel  = (const float*)d_in[1];
    const float* mass = (const float*)d_in[2];
    float* out = (float*)d_out;
    int n = in_sizes[2];
    int blocks = (n + 255) / 256;

    // XCD-path ws: [tile_cnt 1MB][lists 64MB][ovf_cnt 256B][ovf_list 256KB]
    size_t x_off_lists = (size_t)NXCD * NTILES4 * 4;                        // 1 MB
    size_t x_off_ovf   = x_off_lists + (size_t)NXCD * NTILES4 * XCAP * 16;  // +64 MB
    size_t need_xcd    = x_off_ovf + 256 + (size_t)OVF_MAX * 4;

    // Sorted-path ws: [counts/cursors 8MB][offsets 8MB][records n*32][partials]
    size_t s_off_offsets  = (size_t)NUM_CELLS * 4;
    size_t s_off_records  = s_off_offsets + (size_t)NUM_CELLS * 4;
    size_t s_off_partials = s_off_records + (size_t)n * 32;
    size_t need_sorted    = s_off_partials + (size_t)SCAN_BLKS * 4;

    if (ws_size >= need_xcd) {
        char* ws = (char*)d_ws;
        unsigned int* tile_cnt = (unsigned int*)ws;
        uint4* lists  = (uint4*)(ws + x_off_lists);
        int* ovf_cnt  = (int*)(ws + x_off_ovf);
        int* ovf_list = ovf_cnt + 64;

        (void)hipMemsetAsync(tile_cnt, 0, x_off_lists, stream);
        (void)hipMemsetAsync(ovf_cnt, 0, 4, stream);
        xcd_place_kernel<<<(n + 511) / 512, 256, 0, stream>>>(
            pos, vel, mass, tile_cnt, lists, ovf_cnt, ovf_list, n);
        xcd_gather_kernel<<<NTILES4 / 8, 512, 0, stream>>>(
            lists, tile_cnt, (float4*)out);
        fixup_kernel<<<32, 256, 0, stream>>>(pos, vel, mass, ovf_cnt,
                                             ovf_list, out);
    } else if (ws_size >= need_sorted) {
        char* ws = (char*)d_ws;
        int* counts   = (int*)ws;                    // reused as cursors
        int* offsets  = (int*)(ws + s_off_offsets);
        float4* records = (float4*)(ws + s_off_records);
        int* partials = (int*)(ws + s_off_partials);

        (void)hipMemsetAsync(counts, 0, (size_t)NUM_CELLS * 4, stream);
        s_hist_kernel<<<blocks, 256, 0, stream>>>(pos, counts, n);
        s_scan_partials_kernel<<<SCAN_BLKS, 256, 0, stream>>>(counts, partials);
        s_scan_tops_kernel<<<1, 1024, 0, stream>>>(partials);
        s_scan_final_kernel<<<SCAN_BLKS, 256, 0, stream>>>(counts, partials,
                                                           offsets, counts);
        s_binplace_kernel<<<blocks, 256, 0, stream>>>(pos, vel, mass, counts,
                                                      records, n);
        s_node_gather_kernel<<<NUM_CELLS / 256, 256, 0, stream>>>(
            records, offsets, counts, (float4*)out);
    } else {
        (void)hipMemsetAsync(out, 0, (size_t)out_size * sizeof(float), stream);
        p2g_scatter_kernel<<<blocks, 256, 0, stream>>>(pos, vel, mass, out, n);
    }
}